// Round 1
// baseline (7727.748 us; speedup 1.0000x reference)
//
#include <hip/hip_runtime.h>
#include <cstdint>
#include <cstddef>

// GPT-2 small-ish forward: L=4, B=2, S=1024, D=768, H=12, HD=64, FF=3072, V=50257
#define D_MODEL 768
#define NHEAD   12
#define HDIM    64
#define SEQ     1024
#define NTOK    2048      // B*S
#define FFDIM   3072
#define NLAYER  4
#define VOCAB   50257
#define QKVD    2304      // 3*D

typedef float f32x4 __attribute__((ext_vector_type(4)));
typedef __bf16 bf16x8 __attribute__((ext_vector_type(8)));
typedef unsigned short ushort8 __attribute__((ext_vector_type(8)));

__device__ __forceinline__ unsigned short f2bf(float f) {
  unsigned int u = __float_as_uint(f);
  return (unsigned short)((u + 0x7FFFu + ((u >> 16) & 1u)) >> 16);
}

// ---------------- embedding: x = tok_emb[ids] + pos_emb ----------------
__global__ __launch_bounds__(256) void k_embed(const int* __restrict__ ids,
                                               const float* __restrict__ tok,
                                               const float* __restrict__ pos,
                                               float* __restrict__ x) {
  int gid = blockIdx.x * 256 + threadIdx.x;   // over NTOK*192 float4s
  int t = gid / 192, f = gid - t * 192;
  int id = ids[t];
  const float4* tp = (const float4*)tok;
  const float4* pp = (const float4*)pos;
  float4 a = tp[(size_t)id * 192 + f];
  float4 b = pp[(size_t)(t & (SEQ - 1)) * 192 + f];
  float4 o; o.x = a.x + b.x; o.y = a.y + b.y; o.z = a.z + b.z; o.w = a.w + b.w;
  ((float4*)x)[gid] = o;
}

// ---------------- LayerNorm (row of 768) ----------------
__global__ __launch_bounds__(256) void k_ln(const float* __restrict__ x,
                                            const float* __restrict__ w,
                                            const float* __restrict__ b,
                                            float* __restrict__ out) {
  __shared__ float red[256];
  int row = blockIdx.x, tid = threadIdx.x;
  const float* xr = x + (size_t)row * D_MODEL;
  float v0 = xr[tid], v1 = xr[tid + 256], v2 = xr[tid + 512];
  red[tid] = v0 + v1 + v2;
  __syncthreads();
  for (int o = 128; o > 0; o >>= 1) { if (tid < o) red[tid] += red[tid + o]; __syncthreads(); }
  float mean = red[0] * (1.0f / 768.0f);
  __syncthreads();
  float d0 = v0 - mean, d1 = v1 - mean, d2 = v2 - mean;
  red[tid] = d0 * d0 + d1 * d1 + d2 * d2;
  __syncthreads();
  for (int o = 128; o > 0; o >>= 1) { if (tid < o) red[tid] += red[tid + o]; __syncthreads(); }
  float rstd = rsqrtf(red[0] * (1.0f / 768.0f) + 1e-5f);
  float* orow = out + (size_t)row * D_MODEL;
  orow[tid]       = d0 * rstd * w[tid]       + b[tid];
  orow[tid + 256] = d1 * rstd * w[tid + 256] + b[tid + 256];
  orow[tid + 512] = d2 * rstd * w[tid + 512] + b[tid + 512];
}

// ---------------- attention (fp32), one block per (b,h,q-row) ----------------
__global__ __launch_bounds__(256) void k_attn(const float* __restrict__ qkv,
                                              float* __restrict__ aout) {
  __shared__ float sc[SEQ];
  __shared__ float red[256];
  int bid = blockIdx.x;
  int qrow = bid & (SEQ - 1);
  int h = (bid >> 10) % NHEAD;
  int b = bid / (SEQ * NHEAD);
  int tid = threadIdx.x, lane = tid & 63, wid = tid >> 6;
  size_t tok = (size_t)b * SEQ + qrow;
  float qv = qkv[tok * QKVD + h * 64 + lane];
  size_t kbase = ((size_t)b * SEQ) * QKVD + D_MODEL + h * 64 + lane;
  for (int k = wid; k <= qrow; k += 4) {
    float kv = qkv[kbase + (size_t)k * QKVD];
    float p = qv * kv;
    #pragma unroll
    for (int o = 32; o > 0; o >>= 1) p += __shfl_xor(p, o);
    if (lane == 0) sc[k] = p * 0.125f;   // 1/sqrt(64)
  }
  __syncthreads();
  // row max
  float lm = -1e30f;
  for (int k = tid; k <= qrow; k += 256) lm = fmaxf(lm, sc[k]);
  red[tid] = lm;
  __syncthreads();
  for (int o = 128; o > 0; o >>= 1) { if (tid < o) red[tid] = fmaxf(red[tid], red[tid + o]); __syncthreads(); }
  float m = red[0];
  __syncthreads();
  // exp + sum
  float ls = 0.0f;
  for (int k = tid; k <= qrow; k += 256) { float e = __expf(sc[k] - m); sc[k] = e; ls += e; }
  red[tid] = ls;
  __syncthreads();
  for (int o = 128; o > 0; o >>= 1) { if (tid < o) red[tid] += red[tid + o]; __syncthreads(); }
  float inv = 1.0f / red[0];
  __syncthreads();
  // PV
  int d = lane, g = wid;
  size_t vbase = ((size_t)b * SEQ) * QKVD + 2 * D_MODEL + h * 64 + d;
  float acc = 0.0f;
  for (int k = g; k <= qrow; k += 4) acc += sc[k] * qkv[vbase + (size_t)k * QKVD];
  red[tid] = acc;
  __syncthreads();
  if (wid == 0) {
    float o = (red[d] + red[64 + d] + red[128 + d] + red[192 + d]) * inv;
    aout[tok * D_MODEL + h * 64 + d] = o;
  }
}

// ---------------- GEMM: C[M,N] = A[M,K] @ W[N,K]^T (+bias)(+gelu)(+res) ----------------
#define BM 128
#define BN 128
#define BK 32
#define LDT 40   // BK + 8 pad (keeps 16B alignment, breaks bank conflicts)

__device__ __forceinline__ void cvt_store16(unsigned short* dst,
                                            float4 f0, float4 f1, float4 f2, float4 f3) {
  union { unsigned short u[8]; uint4 v; } p0, p1;
  p0.u[0] = f2bf(f0.x); p0.u[1] = f2bf(f0.y); p0.u[2] = f2bf(f0.z); p0.u[3] = f2bf(f0.w);
  p0.u[4] = f2bf(f1.x); p0.u[5] = f2bf(f1.y); p0.u[6] = f2bf(f1.z); p0.u[7] = f2bf(f1.w);
  p1.u[0] = f2bf(f2.x); p1.u[1] = f2bf(f2.y); p1.u[2] = f2bf(f2.z); p1.u[3] = f2bf(f2.w);
  p1.u[4] = f2bf(f3.x); p1.u[5] = f2bf(f3.y); p1.u[6] = f2bf(f3.z); p1.u[7] = f2bf(f3.w);
  *(uint4*)dst = p0.v;
  *(uint4*)(dst + 8) = p1.v;
}

template<int HAS_BIAS, int DO_GELU, int HAS_RES>
__global__ __launch_bounds__(256) void k_gemm(const float* __restrict__ A,
                                              const float* __restrict__ W,
                                              const float* __restrict__ bias,
                                              const float* __restrict__ res,
                                              float* __restrict__ C,
                                              int N, int K) {
  __shared__ unsigned short As[BM * LDT];
  __shared__ unsigned short Ws[BM * LDT];
  int tid = threadIdx.x, lane = tid & 63, wid = tid >> 6;
  int wm = wid >> 1, wn = wid & 1;          // 2x2 waves, each owns 64x64
  int fr = lane & 15, fq = lane >> 4;
  int bm = blockIdx.y * BM, bn = blockIdx.x * BN;
  int sr = tid >> 1, sc0 = (tid & 1) * 16;  // staging: half row per thread

  f32x4 acc[4][4] = {};

  const float* ap = A + (size_t)(bm + sr) * K + sc0;
  bool wok = (bn + sr) < N;
  const float* wp = W + (size_t)(bn + sr) * K + sc0;
  unsigned short* asw = &As[sr * LDT + sc0];
  unsigned short* wsw = &Ws[sr * LDT + sc0];
  const unsigned short* abase = &As[(wm * 64 + fr) * LDT + fq * 8];
  const unsigned short* wbase = &Ws[(wn * 64 + fr) * LDT + fq * 8];

  for (int k0 = 0; k0 < K; k0 += BK) {
    float4 a0 = *(const float4*)(ap + k0);
    float4 a1 = *(const float4*)(ap + k0 + 4);
    float4 a2 = *(const float4*)(ap + k0 + 8);
    float4 a3 = *(const float4*)(ap + k0 + 12);
    float4 z; z.x = z.y = z.z = z.w = 0.0f;
    float4 w0 = wok ? *(const float4*)(wp + k0)      : z;
    float4 w1 = wok ? *(const float4*)(wp + k0 + 4)  : z;
    float4 w2 = wok ? *(const float4*)(wp + k0 + 8)  : z;
    float4 w3 = wok ? *(const float4*)(wp + k0 + 12) : z;
    cvt_store16(asw, a0, a1, a2, a3);
    cvt_store16(wsw, w0, w1, w2, w3);
    __syncthreads();

    bf16x8 af[4], bf[4];
    #pragma unroll
    for (int m = 0; m < 4; ++m)
      af[m] = __builtin_bit_cast(bf16x8, *(const ushort8*)(abase + m * 16 * LDT));
    #pragma unroll
    for (int n = 0; n < 4; ++n)
      bf[n] = __builtin_bit_cast(bf16x8, *(const ushort8*)(wbase + n * 16 * LDT));
    #pragma unroll
    for (int m = 0; m < 4; ++m)
      #pragma unroll
      for (int n = 0; n < 4; ++n)
        acc[m][n] = __builtin_amdgcn_mfma_f32_16x16x32_bf16(af[m], bf[n], acc[m][n], 0, 0, 0);
    __syncthreads();
  }

  #pragma unroll
  for (int n = 0; n < 4; ++n) {
    int col = bn + wn * 64 + n * 16 + fr;
    if (col >= N) continue;
    float bv = HAS_BIAS ? bias[col] : 0.0f;
    #pragma unroll
    for (int m = 0; m < 4; ++m) {
      #pragma unroll
      for (int j = 0; j < 4; ++j) {
        int row = bm + wm * 64 + m * 16 + fq * 4 + j;
        size_t idx = (size_t)row * N + col;
        float v = acc[m][n][j] + bv;
        if (DO_GELU) v = 0.5f * v * (1.0f + erff(v * 0.70710678118f));
        if (HAS_RES) v += res[idx];
        C[idx] = v;
      }
    }
  }
}

// ---------------- launch ----------------
extern "C" void kernel_launch(void* const* d_in, const int* in_sizes, int n_in,
                              void* d_out, int out_size, void* d_ws, size_t ws_size,
                              hipStream_t stream) {
  const int*   ids    = (const int*)d_in[0];
  const float* tok    = (const float*)d_in[1];
  const float* pos    = (const float*)d_in[2];
  const float* ln1_w  = (const float*)d_in[3];
  const float* ln1_b  = (const float*)d_in[4];
  const float* qkv_w  = (const float*)d_in[5];
  const float* qkv_b  = (const float*)d_in[6];
  const float* out_w  = (const float*)d_in[7];
  const float* out_b  = (const float*)d_in[8];
  const float* ln2_w  = (const float*)d_in[9];
  const float* ln2_b  = (const float*)d_in[10];
  const float* fc1_w  = (const float*)d_in[11];
  const float* fc1_b  = (const float*)d_in[12];
  const float* fc2_w  = (const float*)d_in[13];
  const float* fc2_b  = (const float*)d_in[14];
  const float* lnf_w  = (const float*)d_in[15];
  const float* lnf_b  = (const float*)d_in[16];

  char* ws = (char*)d_ws;
  float* x    = (float*)(ws);                       // 2048*768*4  = 6291456
  float* h    = (float*)(ws + 6291456);             // 6291456
  float* attO = (float*)(ws + 12582912);            // 6291456
  float* qkv  = (float*)(ws + 18874368);            // 2048*2304*4 = 18874368
  float* gbuf = (float*)(ws + 37748736);            // 2048*3072*4 = 25165824
  float* logits = (float*)d_out;

  k_embed<<<NTOK * 192 / 256, 256, 0, stream>>>(ids, tok, pos, x);

  for (int l = 0; l < NLAYER; ++l) {
    k_ln<<<NTOK, 256, 0, stream>>>(x, ln1_w + l * D_MODEL, ln1_b + l * D_MODEL, h);
    k_gemm<1, 0, 0><<<dim3(QKVD / BN, NTOK / BM), 256, 0, stream>>>(
        h, qkv_w + (size_t)l * QKVD * D_MODEL, qkv_b + l * QKVD, nullptr, qkv, QKVD, D_MODEL);
    k_attn<<<2 * NHEAD * SEQ, 256, 0, stream>>>(qkv, attO);
    k_gemm<1, 0, 1><<<dim3(D_MODEL / BN, NTOK / BM), 256, 0, stream>>>(
        attO, out_w + (size_t)l * D_MODEL * D_MODEL, out_b + l * D_MODEL, x, x, D_MODEL, D_MODEL);
    k_ln<<<NTOK, 256, 0, stream>>>(x, ln2_w + l * D_MODEL, ln2_b + l * D_MODEL, h);
    k_gemm<1, 1, 0><<<dim3(FFDIM / BN, NTOK / BM), 256, 0, stream>>>(
        h, fc1_w + (size_t)l * FFDIM * D_MODEL, fc1_b + l * FFDIM, nullptr, gbuf, FFDIM, D_MODEL);
    k_gemm<1, 0, 1><<<dim3(D_MODEL / BN, NTOK / BM), 256, 0, stream>>>(
        gbuf, fc2_w + (size_t)l * D_MODEL * FFDIM, fc2_b + l * D_MODEL, x, x, D_MODEL, FFDIM);
  }

  k_ln<<<NTOK, 256, 0, stream>>>(x, lnf_w, lnf_b, h);
  // lm_head: logits = h @ tok_emb^T, N = 50257 (edge tiles guarded)
  k_gemm<0, 0, 0><<<dim3((VOCAB + BN - 1) / BN, NTOK / BM), 256, 0, stream>>>(
      h, tok, nullptr, nullptr, logits, VOCAB, D_MODEL);
}

// Round 2
// 1149.478 us; speedup vs baseline: 6.7228x; 6.7228x over previous
//
#include <hip/hip_runtime.h>
#include <cstdint>
#include <cstddef>

// GPT-2: L=4, B=2, S=1024, D=768, H=12, HD=64, FF=3072, V=50257
#define D_MODEL 768
#define NHEAD   12
#define SEQ     1024
#define NTOK    2048
#define FFDIM   3072
#define NLAYER  4
#define VOCAB   50257
#define QKVD    2304

typedef float f32x4 __attribute__((ext_vector_type(4)));
typedef __bf16 bf16x8 __attribute__((ext_vector_type(8)));

__device__ __forceinline__ unsigned short f2bf(float f) {
  unsigned int u = __float_as_uint(f);
  return (unsigned short)((u + 0x7FFFu + ((u >> 16) & 1u)) >> 16);
}

// ---------------- fp32 -> bf16 bulk convert (weights, once per call) --------
__global__ __launch_bounds__(256) void k_cvt(const float* __restrict__ in,
                                             unsigned short* __restrict__ out, int n8) {
  int i = blockIdx.x * 256 + threadIdx.x;
  if (i >= n8) return;
  const float4* p = (const float4*)in;
  float4 a = p[2 * i], b = p[2 * i + 1];
  union { unsigned short u[8]; uint4 v; } r;
  r.u[0] = f2bf(a.x); r.u[1] = f2bf(a.y); r.u[2] = f2bf(a.z); r.u[3] = f2bf(a.w);
  r.u[4] = f2bf(b.x); r.u[5] = f2bf(b.y); r.u[6] = f2bf(b.z); r.u[7] = f2bf(b.w);
  ((uint4*)out)[i] = r.v;
}

// ---------------- embedding: x = tok_emb[ids] + pos_emb (fp32) -------------
__global__ __launch_bounds__(256) void k_embed(const int* __restrict__ ids,
                                               const float* __restrict__ tok,
                                               const float* __restrict__ pos,
                                               float* __restrict__ x) {
  int gid = blockIdx.x * 256 + threadIdx.x;   // NTOK*192 float4s
  int t = gid / 192, f = gid - t * 192;
  int id = ids[t];
  float4 a = ((const float4*)tok)[(size_t)id * 192 + f];
  float4 b = ((const float4*)pos)[(size_t)(t & (SEQ - 1)) * 192 + f];
  float4 o; o.x = a.x + b.x; o.y = a.y + b.y; o.z = a.z + b.z; o.w = a.w + b.w;
  ((float4*)x)[gid] = o;
}

// ---------------- LayerNorm: fp32 in, bf16 out ----------------
__global__ __launch_bounds__(256) void k_ln(const float* __restrict__ x,
                                            const float* __restrict__ w,
                                            const float* __restrict__ b,
                                            unsigned short* __restrict__ out) {
  __shared__ float red[256];
  int row = blockIdx.x, tid = threadIdx.x;
  const float* xr = x + (size_t)row * D_MODEL;
  float v0 = xr[tid], v1 = xr[tid + 256], v2 = xr[tid + 512];
  red[tid] = v0 + v1 + v2;
  __syncthreads();
  for (int o = 128; o > 0; o >>= 1) { if (tid < o) red[tid] += red[tid + o]; __syncthreads(); }
  float mean = red[0] * (1.0f / 768.0f);
  __syncthreads();
  float d0 = v0 - mean, d1 = v1 - mean, d2 = v2 - mean;
  red[tid] = d0 * d0 + d1 * d1 + d2 * d2;
  __syncthreads();
  for (int o = 128; o > 0; o >>= 1) { if (tid < o) red[tid] += red[tid + o]; __syncthreads(); }
  float rstd = rsqrtf(red[0] * (1.0f / 768.0f) + 1e-5f);
  unsigned short* orow = out + (size_t)row * D_MODEL;
  orow[tid]       = f2bf(d0 * rstd * w[tid]       + b[tid]);
  orow[tid + 256] = f2bf(d1 * rstd * w[tid + 256] + b[tid + 256]);
  orow[tid + 512] = f2bf(d2 * rstd * w[tid + 512] + b[tid + 512]);
}

// ---------------- MFMA flash attention, 1 wave per (b,h,16 q-rows) ---------
// Swapped QK^T: S^T = mfma(K,Q) so each lane's q = lane&15 is fixed -> m/l/
// rescale are lane scalars. KVBLK=32: two 16-row S^T sub-tiles, P^T
// redistributed to the 16x16x32 B-frag layout with 8 shfl. PV: O^T += V^T @ P^T.
__global__ __launch_bounds__(64) void k_attn(const unsigned short* __restrict__ qkv,
                                             unsigned short* __restrict__ attO) {
  int bid = blockIdx.x;
  int qt = (SEQ / 16 - 1) - (bid & 63);       // big q-tiles first (load balance)
  int h = (bid >> 6) % NHEAD;
  int b = bid / (64 * NHEAD);
  int lane = threadIdx.x;
  int fr = lane & 15, fq = lane >> 4;
  int qb = qt * 16;

  size_t rowQ = (size_t)(b * SEQ + qb + fr) * QKVD + h * 64;
  bf16x8 bq0 = *(const bf16x8*)(qkv + rowQ + fq * 8);
  bf16x8 bq1 = *(const bf16x8*)(qkv + rowQ + 32 + fq * 8);

  float m = -1e30f, ll = 0.0f;
  f32x4 o[4] = {};
  int nkt = (qt >> 1) + 1;
  size_t kvrow0 = (size_t)(b * SEQ) * QKVD;

  for (int kt = 0; kt < nkt; ++kt) {
    int kvb = kt * 32;
    bool diag = (kt == nkt - 1);
    float p[2][4];
    float tm = -1e30f;
    #pragma unroll
    for (int t = 0; t < 2; ++t) {
      size_t rowK = kvrow0 + (size_t)(kvb + t * 16 + fr) * QKVD + D_MODEL + h * 64;
      bf16x8 ak0 = *(const bf16x8*)(qkv + rowK + fq * 8);
      bf16x8 ak1 = *(const bf16x8*)(qkv + rowK + 32 + fq * 8);
      f32x4 st = {};
      st = __builtin_amdgcn_mfma_f32_16x16x32_bf16(ak0, bq0, st, 0, 0, 0);
      st = __builtin_amdgcn_mfma_f32_16x16x32_bf16(ak1, bq1, st, 0, 0, 0);
      #pragma unroll
      for (int j = 0; j < 4; ++j) {
        float s = st[j] * 0.125f;                       // 1/sqrt(64)
        if (diag && (kvb + t * 16 + fq * 4 + j > qb + fr)) s = -1e30f;
        p[t][j] = s;
        tm = fmaxf(tm, s);
      }
    }
    tm = fmaxf(tm, __shfl_xor(tm, 16));
    tm = fmaxf(tm, __shfl_xor(tm, 32));
    float mnew = fmaxf(m, tm);
    float corr = __expf(m - mnew);
    float psum = 0.0f;
    #pragma unroll
    for (int t = 0; t < 2; ++t)
      #pragma unroll
      for (int j = 0; j < 4; ++j) { float e = __expf(p[t][j] - mnew); p[t][j] = e; psum += e; }
    psum += __shfl_xor(psum, 16);
    psum += __shfl_xor(psum, 32);
    ll = ll * corr + psum;
    m = mnew;
    #pragma unroll
    for (int dg = 0; dg < 4; ++dg) {
      o[dg][0] *= corr; o[dg][1] *= corr; o[dg][2] *= corr; o[dg][3] *= corr;
    }
    // pack P^T (k = fq*4+j per sub-tile) and redistribute to B-frag (k = fq*8+j')
    unsigned int lo0 = (unsigned)f2bf(p[0][0]) | ((unsigned)f2bf(p[0][1]) << 16);
    unsigned int hi0 = (unsigned)f2bf(p[0][2]) | ((unsigned)f2bf(p[0][3]) << 16);
    unsigned int lo1 = (unsigned)f2bf(p[1][0]) | ((unsigned)f2bf(p[1][1]) << 16);
    unsigned int hi1 = (unsigned)f2bf(p[1][2]) | ((unsigned)f2bf(p[1][3]) << 16);
    int sA = fr + 16 * ((fq & 1) * 2);
    int sB = sA + 16;
    unsigned int w0a = __shfl(lo0, sA), w0b = __shfl(lo1, sA);
    unsigned int w1a = __shfl(hi0, sA), w1b = __shfl(hi1, sA);
    unsigned int w2a = __shfl(lo0, sB), w2b = __shfl(lo1, sB);
    unsigned int w3a = __shfl(hi0, sB), w3b = __shfl(hi1, sB);
    bool t1 = (fq >> 1) != 0;
    uint4 pw;
    pw.x = t1 ? w0b : w0a;
    pw.y = t1 ? w1b : w1a;
    pw.z = t1 ? w2b : w2a;
    pw.w = t1 ? w3b : w3a;
    bf16x8 pb = __builtin_bit_cast(bf16x8, pw);
    // V^T fragments (A-operand): lane reads V[kvb+fq*8+j][h*64+dg*16+fr]
    size_t vcol = kvrow0 + 2 * D_MODEL + h * 64 + fr;
    #pragma unroll
    for (int dg = 0; dg < 4; ++dg) {
      union { unsigned short u[8]; bf16x8 v; } va;
      #pragma unroll
      for (int j = 0; j < 8; ++j)
        va.u[j] = qkv[vcol + (size_t)(kvb + fq * 8 + j) * QKVD + dg * 16];
      o[dg] = __builtin_amdgcn_mfma_f32_16x16x32_bf16(va.v, pb, o[dg], 0, 0, 0);
    }
  }
  float inv = 1.0f / ll;
  size_t obase = (size_t)(b * SEQ + qb + fr) * D_MODEL + h * 64;
  #pragma unroll
  for (int dg = 0; dg < 4; ++dg)
    #pragma unroll
    for (int j = 0; j < 4; ++j)
      attO[obase + dg * 16 + fq * 4 + j] = f2bf(o[dg][j] * inv);
}

// ---------------- bf16 GEMM: C[M,N] = A[M,K] @ W[N,K]^T, m97 structure -----
// BM=BN=128, BK=64, 4 waves (2x2 of 64x64). global_load_lds width=16 into
// linear LDS; XOR swizzle (16B unit ^= row&7) applied on the global SOURCE
// address and on the ds_read address (rule #21). M assumed 2048 (16 M-tiles).
// 1-D grid, M-fastest + XCD swizzle: W-tiles partition across XCD L2s.
template<int HAS_BIAS, int DO_GELU, int HAS_RES, int OUT_BF16>
__global__ __launch_bounds__(256) void k_gemm(const unsigned short* __restrict__ A,
                                              const unsigned short* __restrict__ W,
                                              const float* __restrict__ bias,
                                              const float* __restrict__ res,
                                              void* __restrict__ Cout,
                                              int N, int K) {
  __shared__ __align__(1024) unsigned short As[128 * 64];
  __shared__ __align__(1024) unsigned short Ws[128 * 64];
  int tid = threadIdx.x, lane = tid & 63, wv = tid >> 6;
  int fr = lane & 15, fq = lane >> 4;
  int wm = wv >> 1, wn = wv & 1;

  int cpx = gridDim.x >> 3;                       // grid % 8 == 0 for all calls
  int id = (blockIdx.x & 7) * cpx + (blockIdx.x >> 3);
  int bm = (id & 15) * 128;                       // M fast: consecutive blocks share W tile
  int bn = (id >> 4) * 128;

  // staging: wave wv owns chunks wv*4..wv*4+3 (1024B each = 8 rows of 128B)
  const unsigned short* pA[4];
  const unsigned short* pW[4];
  unsigned short* ldsA[4];
  unsigned short* ldsW[4];
  #pragma unroll
  for (int i = 0; i < 4; ++i) {
    int c = wv * 4 + i;
    int r = c * 8 + (lane >> 3);
    int up = (lane & 7) ^ (r & 7);                // pre-swizzled source unit
    pA[i] = A + (size_t)(bm + r) * K + up * 8;
    int wr = bn + r; if (wr > N - 1) wr = N - 1;  // lm_head edge clamp
    pW[i] = W + (size_t)wr * K + up * 8;
    ldsA[i] = &As[c * 512];
    ldsW[i] = &Ws[c * 512];
  }

  const unsigned short* aB = As + (wm * 64 + fr) * 64;
  const unsigned short* wB = Ws + (wn * 64 + fr) * 64;
  int sz = fr & 7;
  int u0 = (fq ^ sz) * 8;                          // kk=0 swizzled unit offset
  int u1 = ((4 + fq) ^ sz) * 8;                    // kk=1

  f32x4 acc[4][4] = {};

  for (int k0 = 0; k0 < K; k0 += 64) {
    #pragma unroll
    for (int i = 0; i < 4; ++i) {
      __builtin_amdgcn_global_load_lds(
          (const __attribute__((address_space(1))) unsigned int*)(pA[i] + k0),
          (__attribute__((address_space(3))) unsigned int*)ldsA[i], 16, 0, 0);
      __builtin_amdgcn_global_load_lds(
          (const __attribute__((address_space(1))) unsigned int*)(pW[i] + k0),
          (__attribute__((address_space(3))) unsigned int*)ldsW[i], 16, 0, 0);
    }
    __syncthreads();

    bf16x8 af[4][2], bf[4][2];
    #pragma unroll
    for (int mm = 0; mm < 4; ++mm) {
      af[mm][0] = *(const bf16x8*)(aB + mm * 1024 + u0);
      af[mm][1] = *(const bf16x8*)(aB + mm * 1024 + u1);
    }
    #pragma unroll
    for (int nn = 0; nn < 4; ++nn) {
      bf[nn][0] = *(const bf16x8*)(wB + nn * 1024 + u0);
      bf[nn][1] = *(const bf16x8*)(wB + nn * 1024 + u1);
    }
    #pragma unroll
    for (int mm = 0; mm < 4; ++mm)
      #pragma unroll
      for (int nn = 0; nn < 4; ++nn) {
        acc[mm][nn] = __builtin_amdgcn_mfma_f32_16x16x32_bf16(af[mm][0], bf[nn][0], acc[mm][nn], 0, 0, 0);
        acc[mm][nn] = __builtin_amdgcn_mfma_f32_16x16x32_bf16(af[mm][1], bf[nn][1], acc[mm][nn], 0, 0, 0);
      }
    __syncthreads();
  }

  #pragma unroll
  for (int nn = 0; nn < 4; ++nn) {
    int col = bn + wn * 64 + nn * 16 + fr;
    if (col >= N) continue;
    float bv = HAS_BIAS ? bias[col] : 0.0f;
    #pragma unroll
    for (int mm = 0; mm < 4; ++mm) {
      #pragma unroll
      for (int j = 0; j < 4; ++j) {
        int row = bm + wm * 64 + mm * 16 + fq * 4 + j;
        size_t idx = (size_t)row * N + col;
        float v = acc[mm][nn][j] + bv;
        if (DO_GELU) v = 0.5f * v * (1.0f + erff(v * 0.70710678118f));
        if (HAS_RES) v += res[idx];
        if (OUT_BF16) ((unsigned short*)Cout)[idx] = f2bf(v);
        else          ((float*)Cout)[idx] = v;
      }
    }
  }
}

// ---------------- launch ----------------
extern "C" void kernel_launch(void* const* d_in, const int* in_sizes, int n_in,
                              void* d_out, int out_size, void* d_ws, size_t ws_size,
                              hipStream_t stream) {
  const int*   ids    = (const int*)d_in[0];
  const float* tok    = (const float*)d_in[1];
  const float* pos    = (const float*)d_in[2];
  const float* ln1_w  = (const float*)d_in[3];
  const float* ln1_b  = (const float*)d_in[4];
  const float* qkv_w  = (const float*)d_in[5];
  const float* qkv_b  = (const float*)d_in[6];
  const float* out_w  = (const float*)d_in[7];
  const float* out_b  = (const float*)d_in[8];
  const float* ln2_w  = (const float*)d_in[9];
  const float* ln2_b  = (const float*)d_in[10];
  const float* fc1_w  = (const float*)d_in[11];
  const float* fc1_b  = (const float*)d_in[12];
  const float* fc2_w  = (const float*)d_in[13];
  const float* fc2_b  = (const float*)d_in[14];
  const float* lnf_w  = (const float*)d_in[15];
  const float* lnf_b  = (const float*)d_in[16];

  char* ws = (char*)d_ws;
  float*          x    = (float*)(ws);                         // 6,291,456
  unsigned short* qkvb = (unsigned short*)(ws + 6291456);      // 9,437,184
  unsigned short* h    = (unsigned short*)(ws + 15728640);     // 3,145,728
  unsigned short* attO = (unsigned short*)(ws + 18874368);     // 3,145,728
  unsigned short* gbuf = (unsigned short*)(ws + 22020096);     // 12,582,912
  unsigned short* wq   = (unsigned short*)(ws + 34603008);     // 14,155,776
  unsigned short* wo   = (unsigned short*)(ws + 48758784);     //  4,718,592
  unsigned short* w1   = (unsigned short*)(ws + 53477376);     // 18,874,368
  unsigned short* w2   = (unsigned short*)(ws + 72351744);     // 18,874,368
  unsigned short* wtok = (unsigned short*)(ws + 91226112);     // 77,194,752 (ends 168,420,864)
  float* logits = (float*)d_out;

  // weight conversions (once per call)
  {
    int n8;
    n8 = NLAYER * QKVD * D_MODEL / 8;
    k_cvt<<<(n8 + 255) / 256, 256, 0, stream>>>(qkv_w, wq, n8);
    n8 = NLAYER * D_MODEL * D_MODEL / 8;
    k_cvt<<<(n8 + 255) / 256, 256, 0, stream>>>(out_w, wo, n8);
    n8 = NLAYER * FFDIM * D_MODEL / 8;
    k_cvt<<<(n8 + 255) / 256, 256, 0, stream>>>(fc1_w, w1, n8);
    k_cvt<<<(n8 + 255) / 256, 256, 0, stream>>>(fc2_w, w2, n8);
    n8 = VOCAB * D_MODEL / 8;
    k_cvt<<<(n8 + 255) / 256, 256, 0, stream>>>(tok, wtok, n8);
  }

  k_embed<<<NTOK * 192 / 256, 256, 0, stream>>>(ids, tok, pos, x);

  for (int l = 0; l < NLAYER; ++l) {
    k_ln<<<NTOK, 256, 0, stream>>>(x, ln1_w + l * D_MODEL, ln1_b + l * D_MODEL, h);
    k_gemm<1, 0, 0, 1><<<16 * (QKVD / 128), 256, 0, stream>>>(
        h, wq + (size_t)l * QKVD * D_MODEL, qkv_b + l * QKVD, nullptr, qkvb, QKVD, D_MODEL);
    k_attn<<<2 * NHEAD * (SEQ / 16), 64, 0, stream>>>(qkvb, attO);
    k_gemm<1, 0, 1, 0><<<16 * (D_MODEL / 128), 256, 0, stream>>>(
        attO, wo + (size_t)l * D_MODEL * D_MODEL, out_b + l * D_MODEL, x, x, D_MODEL, D_MODEL);
    k_ln<<<NTOK, 256, 0, stream>>>(x, ln2_w + l * D_MODEL, ln2_b + l * D_MODEL, h);
    k_gemm<1, 1, 0, 1><<<16 * (FFDIM / 128), 256, 0, stream>>>(
        h, w1 + (size_t)l * FFDIM * D_MODEL, fc1_b + l * FFDIM, nullptr, gbuf, FFDIM, D_MODEL);
    k_gemm<1, 0, 1, 0><<<16 * (D_MODEL / 128), 256, 0, stream>>>(
        gbuf, w2 + (size_t)l * D_MODEL * FFDIM, fc2_b + l * D_MODEL, x, x, D_MODEL, FFDIM);
  }

  k_ln<<<NTOK, 256, 0, stream>>>(x, lnf_w, lnf_b, h);
  // lm_head: logits = h @ tok_bf16^T, N = 50257 (edge tiles clamped+guarded)
  k_gemm<0, 0, 0, 0><<<16 * ((VOCAB + 127) / 128), 256, 0, stream>>>(
      h, wtok, nullptr, nullptr, logits, VOCAB, D_MODEL);
}